// Round 14
// baseline (507.313 us; speedup 1.0000x reference)
//
#include <hip/hip_runtime.h>
#include <hip/hip_cooperative_groups.h>

namespace cg = cooperative_groups;

#define D 64
#define EPSV 1e-9f

typedef __attribute__((ext_vector_type(8))) short bf8_t;   // 8 x bf16
typedef __attribute__((ext_vector_type(4))) float f4_t;

__device__ inline float bf2f(short u) {
    union { unsigned int i; float f; } v;
    v.i = ((unsigned int)(unsigned short)u) << 16;
    return v.f;
}
__device__ inline unsigned short f2bf(float f) {  // round-nearest-even
    union { float f; unsigned int i; } v; v.f = f;
    unsigned int r = v.i + 0x7fff + ((v.i >> 16) & 1);
    return (unsigned short)(r >> 16);
}

// ================= shared device phases (r12 math, byte-identical) ==========

__device__ __forceinline__ void agg_body(
    const unsigned short* __restrict__ X, unsigned short* __restrict__ M,
    const int* __restrict__ row_off, const int* __restrict__ edge_src,
    const float* __restrict__ edge_w, int n_nodes, int lane, int task)
{
    const int h    = lane >> 5;
    const int slot = (lane >> 3) & 3;
    const int fo   = (lane & 7) * 8;

    int node = task * 2 + h;
    if (node >= n_nodes) node = n_nodes - 1;

    const int s = row_off[node];
    const int e = row_off[node + 1];
    const int deg = e - s;
    const int od  = __shfl_xor(deg, 32);
    const int degmax = deg > od ? deg : od;   // wave-uniform

    float acc[8];
    #pragma unroll
    for (int m = 0; m < 8; ++m) acc[m] = 0.f;
    float wsum = 0.f;

    {   // rounds 0-3: batched meta, 4 independent full-row gathers
        float w[4]; int sc[4];
        #pragma unroll
        for (int r = 0; r < 4; ++r) {
            const int  ej = s + r * 4 + slot;
            const bool v  = ej < e;
            w[r]  = v ? edge_w[ej] : 0.f;
            sc[r] = v ? edge_src[ej] : 0;
        }
        bf8_t f[4];
        #pragma unroll
        for (int r = 0; r < 4; ++r) f[r] = *(const bf8_t*)(X + sc[r] * 64 + fo);
        #pragma unroll
        for (int r = 0; r < 4; ++r) {
            #pragma unroll
            for (int m = 0; m < 8; ++m) acc[m] = fmaf(w[r], bf2f(f[r][m]), acc[m]);
            wsum += w[r];
        }
    }
    if (degmax > 16) {   // rounds 4-7
        float w[4]; int sc[4];
        #pragma unroll
        for (int r = 0; r < 4; ++r) {
            const int  ej = s + 16 + r * 4 + slot;
            const bool v  = ej < e;
            w[r]  = v ? edge_w[ej] : 0.f;
            sc[r] = v ? edge_src[ej] : 0;
        }
        bf8_t f[4];
        #pragma unroll
        for (int r = 0; r < 4; ++r) f[r] = *(const bf8_t*)(X + sc[r] * 64 + fo);
        #pragma unroll
        for (int r = 0; r < 4; ++r) {
            #pragma unroll
            for (int m = 0; m < 8; ++m) acc[m] = fmaf(w[r], bf2f(f[r][m]), acc[m]);
            wsum += w[r];
        }
    }
    for (int base = 32; base < degmax; base += 16) {  // rare tail
        float w[4]; int sc[4];
        #pragma unroll
        for (int r = 0; r < 4; ++r) {
            const int  ej = s + base + r * 4 + slot;
            const bool v  = ej < e;
            w[r]  = v ? edge_w[ej] : 0.f;
            sc[r] = v ? edge_src[ej] : 0;
        }
        bf8_t f[4];
        #pragma unroll
        for (int r = 0; r < 4; ++r) f[r] = *(const bf8_t*)(X + sc[r] * 64 + fo);
        #pragma unroll
        for (int r = 0; r < 4; ++r) {
            #pragma unroll
            for (int m = 0; m < 8; ++m) acc[m] = fmaf(w[r], bf2f(f[r][m]), acc[m]);
            wsum += w[r];
        }
    }

    #pragma unroll
    for (int off = 8; off <= 16; off <<= 1) {
        #pragma unroll
        for (int m = 0; m < 8; ++m) acc[m] += __shfl_xor(acc[m], off);
        wsum += __shfl_xor(wsum, off);
    }

    const float inv = 1.0f / (wsum + EPSV);
    if (slot == 0) {
        bf8_t mv;
        #pragma unroll
        for (int m = 0; m < 8; ++m) mv[m] = (short)f2bf(acc[m] * inv);
        *(bf8_t*)(M + node * 64 + fo) = mv;
    }
}

// one (tile, t) slice: 16 rows x 16 cols, 4 MFMA. bfr = 16 VGPR.
template<int OUT_F32>
__device__ __forceinline__ void gemm_slice(
    const unsigned short* __restrict__ X, const unsigned short* __restrict__ M,
    const unsigned short* __restrict__ Wpack,
    const float* __restrict__ b0, const float* __restrict__ b1,
    void* __restrict__ outp, int n_nodes, int lane, int task)
{
    const int t    = task & 3;
    const int tile = task >> 2;

    bf8_t bfr[4];
    #pragma unroll
    for (int kk = 0; kk < 4; ++kk)
        bfr[kk] = *(const bf8_t*)(Wpack + ((t * 4 + kk) * 64 + lane) * 8);

    const int col  = t * 16 + (lane & 15);
    const float bias = b0[col] + b1[col];

    const int koff = (lane >> 4) * 8;
    const int rowbase = tile * 16;
    int arow = rowbase + (lane & 15); if (arow >= n_nodes) arow = n_nodes - 1;

    bf8_t af[4];
    af[0] = *(const bf8_t*)(X + arow * 64 + koff);
    af[1] = *(const bf8_t*)(X + arow * 64 + 32 + koff);
    af[2] = *(const bf8_t*)(M + arow * 64 + koff);
    af[3] = *(const bf8_t*)(M + arow * 64 + 32 + koff);

    f4_t acc = (f4_t){0.f, 0.f, 0.f, 0.f};
    #pragma unroll
    for (int kk = 0; kk < 4; ++kk)
        acc = __builtin_amdgcn_mfma_f32_16x16x32_bf16(af[kk], bfr[kk], acc, 0, 0, 0);

    #pragma unroll
    for (int r = 0; r < 4; ++r) {
        const int row = rowbase + (lane >> 4) * 4 + r;
        if (row < n_nodes) {
            const float v = fmaxf(acc[r] + bias, 0.0f);
            if (OUT_F32) ((float*)outp)[row * 64 + col] = v;
            else         ((unsigned short*)outp)[row * 64 + col] = f2bf(v);
        }
    }
}

// ================= cooperative all-in-one (64-VGPR budget) ==================
__global__ __launch_bounds__(256, 8) void fused_all(
    const float* __restrict__ node_feats,
    const int*   __restrict__ edge_src,
    const int*   __restrict__ edge_dst,
    const float* __restrict__ edge_w,
    const float* __restrict__ W0,
    const float* __restrict__ b0,
    const float* __restrict__ W1,
    const float* __restrict__ b1,
    int* __restrict__ row_off,
    unsigned short* __restrict__ Wpack,
    unsigned short* __restrict__ X0,
    unsigned short* __restrict__ X1,
    unsigned short* __restrict__ M,
    float* __restrict__ outp,
    int n_nodes, int n_edges)
{
    cg::grid_group grid = cg::this_grid();

    const int lane   = threadIdx.x & 63;
    const int wib    = threadIdx.x >> 6;
    const int tid    = blockIdx.x * 256 + threadIdx.x;
    const int nthr   = gridDim.x * 256;
    const int wave0  = blockIdx.x * 4 + wib;
    const int nwaves = gridDim.x * 4;

    // ---- prep ----
    for (int i = tid; i < n_nodes * 16; i += nthr) {      // cvt f32 -> bf16
        const float4 v = ((const float4*)node_feats)[i];
        const int row = i >> 4, c4 = (i & 15) * 4;
        unsigned short* p = X0 + row * 64 + c4;
        p[0] = f2bf(v.x); p[1] = f2bf(v.y); p[2] = f2bf(v.z); p[3] = f2bf(v.w);
    }
    for (int idx = tid; idx < 8192; idx += nthr) {        // Wpack
        const int j = idx & 7, ln = (idx >> 3) & 63, kk = (idx >> 9) & 3, t = idx >> 11;
        const int k = kk * 32 + (ln >> 4) * 8 + j;
        const int d = t * 16 + (ln & 15);
        const float v = (k < D) ? W0[d * D + k] : W1[d * D + (k - D)];
        Wpack[idx] = f2bf(v);
    }
    for (int i = tid; i <= n_edges; i += nthr) {          // row_off scatter
        const int prev = (i == 0) ? -1 : edge_dst[i - 1];
        const int cur  = (i == n_edges) ? n_nodes : edge_dst[i];
        for (int n = prev + 1; n <= cur; ++n) row_off[n] = i;
    }
    grid.sync();

    const int atasks = (n_nodes + 1) / 2;        // 25000
    const int gtasks = ((n_nodes + 15) / 16) * 4; // 12500

    // ---- layer 0 ----
    for (int task = wave0; task < atasks; task += nwaves)
        agg_body(X0, M, row_off, edge_src, edge_w, n_nodes, lane, task);
    grid.sync();
    for (int task = wave0; task < gtasks; task += nwaves)
        gemm_slice<0>(X0, M, Wpack, b0, b1, X1, n_nodes, lane, task);
    grid.sync();

    // ---- layer 1 ----
    for (int task = wave0; task < atasks; task += nwaves)
        agg_body(X1, M, row_off, edge_src, edge_w, n_nodes, lane, task);
    grid.sync();
    for (int task = wave0; task < gtasks; task += nwaves)
        gemm_slice<1>(X1, M, Wpack, b0, b1, outp, n_nodes, lane, task);
}

// ================= fallback kernels (exact r12 structure) ===================
__global__ void prep_kernel(const float* __restrict__ node_feats,
                            const int*   __restrict__ edge_dst,
                            const float* __restrict__ W0,
                            const float* __restrict__ W1,
                            int* __restrict__ row_off,
                            unsigned short* __restrict__ Wpack,
                            unsigned short* __restrict__ X,
                            int n_nodes, int n_edges, int cvtb)
{
    const int bid = blockIdx.x, tid = threadIdx.x;
    if (bid < cvtb) {
        const int i = bid * 256 + tid;
        if (i < n_nodes * 16) {
            const float4 v = ((const float4*)node_feats)[i];
            const int row = i >> 4, c4 = (i & 15) * 4;
            unsigned short* p = X + row * 64 + c4;
            p[0] = f2bf(v.x); p[1] = f2bf(v.y); p[2] = f2bf(v.z); p[3] = f2bf(v.w);
        }
    } else if (bid < cvtb + 32) {
        const int idx = (bid - cvtb) * 256 + tid;
        const int j = idx & 7, lane = (idx >> 3) & 63, kk = (idx >> 9) & 3, t = idx >> 11;
        const int k = kk * 32 + (lane >> 4) * 8 + j;
        const int d = t * 16 + (lane & 15);
        const float v = (k < D) ? W0[d * D + k] : W1[d * D + (k - D)];
        Wpack[idx] = f2bf(v);
    } else {
        const int i = (bid - cvtb - 32) * 256 + tid;
        if (i <= n_edges) {
            const int prev = (i == 0) ? -1 : edge_dst[i - 1];
            const int cur  = (i == n_edges) ? n_nodes : edge_dst[i];
            for (int n = prev + 1; n <= cur; ++n) row_off[n] = i;
        }
    }
}

__global__ __launch_bounds__(256, 8) void aggregate_kernel(
    const unsigned short* __restrict__ X, unsigned short* __restrict__ M,
    const int* __restrict__ row_off, const int* __restrict__ edge_src,
    const float* __restrict__ edge_w, int n_nodes)
{
    const int lane = threadIdx.x & 63;
    const int wib  = threadIdx.x >> 6;
    agg_body(X, M, row_off, edge_src, edge_w, n_nodes, lane, blockIdx.x * 4 + wib);
}

template<int OUT_F32>
__global__ __launch_bounds__(256, 8) void gemm_kernel(
    const unsigned short* __restrict__ X, const unsigned short* __restrict__ M,
    const unsigned short* __restrict__ Wpack,
    const float* __restrict__ b0, const float* __restrict__ b1,
    void* __restrict__ outp, int n_nodes, int gtasks)
{
    const int lane = threadIdx.x & 63;
    const int wib  = threadIdx.x >> 6;
    const int task = blockIdx.x * 4 + wib;
    if (task < gtasks)
        gemm_slice<OUT_F32>(X, M, Wpack, b0, b1, outp, n_nodes, lane, task);
}

extern "C" void kernel_launch(void* const* d_in, const int* in_sizes, int n_in,
                              void* d_out, int out_size, void* d_ws, size_t ws_size,
                              hipStream_t stream) {
    const float* node_feats = (const float*)d_in[0];
    const int*   edge_src   = (const int*)  d_in[1];
    const int*   edge_dst   = (const int*)  d_in[2];
    const float* edge_w     = (const float*)d_in[3];
    const float* W0         = (const float*)d_in[4];
    const float* b0         = (const float*)d_in[5];
    const float* W1         = (const float*)d_in[6];
    const float* b1         = (const float*)d_in[7];

    int n_nodes = in_sizes[0] / D;   // 50000
    int n_edges = in_sizes[1];       // 800000

    char* ws = (char*)d_ws;
    int*            row_off = (int*)ws;
    unsigned short* Wpack   = (unsigned short*)(ws + 204800);
    const size_t base = 237568;
    unsigned short* X0 = (unsigned short*)(ws + base);
    unsigned short* X1 = (unsigned short*)(ws + base + 6400000);
    unsigned short* M  = (unsigned short*)(ws + base + 12800000);
    float* outp = (float*)d_out;

    // ---- try cooperative path (query-clamped, checked) ----
    int dev = 0, numCU = 0, maxB = 0;
    bool coop = (hipGetDevice(&dev) == hipSuccess) &&
                (hipDeviceGetAttribute(&numCU, hipDeviceAttributeMultiprocessorCount, dev) == hipSuccess) &&
                (hipOccupancyMaxActiveBlocksPerMultiprocessor(&maxB, (const void*)fused_all, 256, 0) == hipSuccess) &&
                numCU > 0 && maxB > 0;
    if (coop) {
        int grid = maxB * numCU;
        if (grid > 2048) grid = 2048;
        void* args[] = {
            (void*)&node_feats, (void*)&edge_src, (void*)&edge_dst, (void*)&edge_w,
            (void*)&W0, (void*)&b0, (void*)&W1, (void*)&b1,
            (void*)&row_off, (void*)&Wpack, (void*)&X0, (void*)&X1, (void*)&M,
            (void*)&outp, (void*)&n_nodes, (void*)&n_edges
        };
        if (hipLaunchCooperativeKernel((void*)fused_all, dim3(grid), dim3(256),
                                       args, 0, stream) == hipSuccess)
            return;
    }

    // ---- fallback: r12 five-kernel sequence ----
    const int cvtb = (n_nodes * 16 + 255) / 256;
    const int offb = (n_edges + 1 + 255) / 256;
    prep_kernel<<<cvtb + 32 + offb, 256, 0, stream>>>(node_feats, edge_dst, W0, W1,
                                                      row_off, Wpack, X0,
                                                      n_nodes, n_edges, cvtb);
    const int atasks = (n_nodes + 1) / 2;
    const int gtasks = ((n_nodes + 15) / 16) * 4;
    const int agrid  = (atasks + 3) / 4;
    const int ggrid  = (gtasks + 3) / 4;

    aggregate_kernel<<<agrid, 256, 0, stream>>>(X0, M, row_off, edge_src, edge_w, n_nodes);
    gemm_kernel<0><<<ggrid, 256, 0, stream>>>(X0, M, Wpack, b0, b1, X1, n_nodes, gtasks);
    aggregate_kernel<<<agrid, 256, 0, stream>>>(X1, M, row_off, edge_src, edge_w, n_nodes);
    gemm_kernel<1><<<ggrid, 256, 0, stream>>>(X1, M, Wpack, b0, b1, d_out, n_nodes, gtasks);
}

// Round 15
// 69.928 us; speedup vs baseline: 7.2548x; 7.2548x over previous
//
#include <hip/hip_runtime.h>

#define D 64
#define EPSV 1e-9f

typedef __attribute__((ext_vector_type(8))) short bf8_t;   // 8 x bf16
typedef __attribute__((ext_vector_type(4))) float f4_t;

__device__ inline float bf2f(short u) {
    union { unsigned int i; float f; } v;
    v.i = ((unsigned int)(unsigned short)u) << 16;
    return v.f;
}
__device__ inline unsigned short f2bf(float f) {  // round-nearest-even
    union { float f; unsigned int i; } v; v.f = f;
    unsigned int r = v.i + 0x7fff + ((v.i >> 16) & 1);
    return (unsigned short)(r >> 16);
}

// --- Fused prep: cvt | wpack | row_off boundary scatter (r12-proven) ---
__global__ void prep_kernel(const float* __restrict__ node_feats,
                            const int*   __restrict__ edge_dst,
                            const float* __restrict__ W0,
                            const float* __restrict__ W1,
                            int* __restrict__ row_off,
                            unsigned short* __restrict__ Wpack,
                            unsigned short* __restrict__ X,   // [n][64] bf16
                            int n_nodes, int n_edges, int cvtb)
{
    const int bid = blockIdx.x, tid = threadIdx.x;
    if (bid < cvtb) {
        const int i = bid * 256 + tid;
        if (i < n_nodes * 16) {
            const float4 v = ((const float4*)node_feats)[i];
            const int row = i >> 4, c4 = (i & 15) * 4;
            unsigned short* p = X + row * 64 + c4;
            p[0] = f2bf(v.x); p[1] = f2bf(v.y); p[2] = f2bf(v.z); p[3] = f2bf(v.w);
        }
    } else if (bid < cvtb + 32) {
        // Wpack[((t*4+kk)*64+lane)*8+j] = W[k][col], k=kk*32+(lane>>4)*8+j, col=t*16+(lane&15)
        const int idx = (bid - cvtb) * 256 + tid;
        const int j = idx & 7, lane = (idx >> 3) & 63, kk = (idx >> 9) & 3, t = idx >> 11;
        const int k = kk * 32 + (lane >> 4) * 8 + j;
        const int d = t * 16 + (lane & 15);
        const float v = (k < D) ? W0[d * D + k] : W1[d * D + (k - D)];
        Wpack[idx] = f2bf(v);
    } else {
        const int i = (bid - cvtb - 32) * 256 + tid;   // i in [0, n_edges]
        if (i <= n_edges) {
            const int prev = (i == 0) ? -1 : edge_dst[i - 1];
            const int cur  = (i == n_edges) ? n_nodes : edge_dst[i];
            for (int n = prev + 1; n <= cur; ++n) row_off[n] = i;
        }
    }
}

// --- one batch of 4 rounds: edges [b, b+8) of this lane's node, 4 gathers in flight
__device__ __forceinline__ void agg_batch8(
    const unsigned short* __restrict__ X,
    const int* __restrict__ edge_src, const float* __restrict__ edge_w,
    int s, int e, int b, int slot, int fo,
    float acc[8], float& wsum)
{
    float w[4]; int sc[4];
    #pragma unroll
    for (int r = 0; r < 4; ++r) {
        const int  ej = s + b + r * 2 + slot;
        const bool v  = ej < e;
        w[r]  = v ? edge_w[ej] : 0.f;
        sc[r] = v ? edge_src[ej] : 0;
    }
    bf8_t f[4];
    #pragma unroll
    for (int r = 0; r < 4; ++r) f[r] = *(const bf8_t*)(X + sc[r] * 64 + fo);
    #pragma unroll
    for (int r = 0; r < 4; ++r) {
        #pragma unroll
        for (int m = 0; m < 8; ++m) acc[m] = fmaf(w[r], bf2f(f[r][m]), acc[m]);
        wsum += w[r];
    }
}

// --- Fused layer: block = one 16-row tile. Phase A: wave w aggregates rows
// w*4..w*4+3 (quarter-wave/node, 8 gathers in flight) -> LDS msg.
// Phase B: wave w computes output cols [w*16, w*16+16) via 4 MFMA.
template<int OUT_F32>
__global__ __launch_bounds__(256, 6) void layer_fused(
    const unsigned short* __restrict__ Xin,     // [n][64] bf16
    const int*   __restrict__ row_off,
    const int*   __restrict__ edge_src,
    const float* __restrict__ edge_w,
    const unsigned short* __restrict__ Wpack,   // fragment-packed, 8192 bf16
    const float* __restrict__ b0,
    const float* __restrict__ b1,
    void* __restrict__ outp,
    int n_nodes)
{
    __shared__ __align__(16) unsigned short lds_msg[16][72];  // +pad: conflict-free

    const int lane = threadIdx.x & 63;
    const int w    = threadIdx.x >> 6;
    const int rowbase = blockIdx.x * 16;

    // ---------- Phase A ----------
    const int q    = lane >> 4;          // quarter = node select (0..3)
    const int slot = (lane >> 3) & 1;    // 2 edge slots per node
    const int fo   = (lane & 7) * 8;     // 16B piece of the 128B row

    int node = rowbase + w * 4 + q;
    if (node >= n_nodes) node = n_nodes - 1;
    const int s = row_off[node];
    const int e = row_off[node + 1];
    const int deg = e - s;
    int dm = deg;
    dm = max(dm, __shfl_xor(dm, 16));
    dm = max(dm, __shfl_xor(dm, 32));    // wave-uniform max over the 4 nodes

    float acc[8];
    #pragma unroll
    for (int m = 0; m < 8; ++m) acc[m] = 0.f;
    float wsum = 0.f;

    agg_batch8(Xin, edge_src, edge_w, s, e, 0, slot, fo, acc, wsum);
    agg_batch8(Xin, edge_src, edge_w, s, e, 8, slot, fo, acc, wsum);
    if (dm > 16) {
        agg_batch8(Xin, edge_src, edge_w, s, e, 16, slot, fo, acc, wsum);
        agg_batch8(Xin, edge_src, edge_w, s, e, 24, slot, fo, acc, wsum);
    }
    for (int base = 32; base < dm; base += 16) {   // rare tail
        agg_batch8(Xin, edge_src, edge_w, s, e, base, slot, fo, acc, wsum);
        agg_batch8(Xin, edge_src, edge_w, s, e, base + 8, slot, fo, acc, wsum);
    }

    // combine the 2 slots (lane bit 3)
    #pragma unroll
    for (int m = 0; m < 8; ++m) acc[m] += __shfl_xor(acc[m], 8);
    wsum += __shfl_xor(wsum, 8);

    if ((lane & 8) == 0) {               // slot-0 lanes: 8 x 16B = full msg row
        const float inv = 1.0f / (wsum + EPSV);
        bf8_t mv;
        #pragma unroll
        for (int m = 0; m < 8; ++m) mv[m] = (short)f2bf(acc[m] * inv);
        *(bf8_t*)(&lds_msg[w * 4 + q][fo]) = mv;
    }

    __syncthreads();

    // ---------- Phase B: MFMA, wave w owns cols w*16..w*16+15 ----------
    bf8_t bfr[4];
    #pragma unroll
    for (int kk = 0; kk < 4; ++kk)
        bfr[kk] = *(const bf8_t*)(Wpack + ((w * 4 + kk) * 64 + lane) * 8);

    const int arow16 = lane & 15;
    const int koff   = (lane >> 4) * 8;
    int arow = rowbase + arow16; if (arow >= n_nodes) arow = n_nodes - 1;

    bf8_t af[4];
    af[0] = *(const bf8_t*)(Xin + arow * 64 + koff);        // k  0..31
    af[1] = *(const bf8_t*)(Xin + arow * 64 + 32 + koff);   // k 32..63
    af[2] = *(const bf8_t*)(&lds_msg[arow16][koff]);        // k 64..95
    af[3] = *(const bf8_t*)(&lds_msg[arow16][koff + 32]);   // k 96..127

    f4_t acc4 = (f4_t){0.f, 0.f, 0.f, 0.f};
    #pragma unroll
    for (int kk = 0; kk < 4; ++kk)
        acc4 = __builtin_amdgcn_mfma_f32_16x16x32_bf16(af[kk], bfr[kk], acc4, 0, 0, 0);

    const int col  = w * 16 + (lane & 15);
    const float bias = b0[col] + b1[col];
    #pragma unroll
    for (int r = 0; r < 4; ++r) {
        const int row = rowbase + (lane >> 4) * 4 + r;
        if (row < n_nodes) {
            const float v = fmaxf(acc4[r] + bias, 0.0f);
            if (OUT_F32) ((float*)outp)[row * 64 + col] = v;
            else         ((unsigned short*)outp)[row * 64 + col] = f2bf(v);
        }
    }
}

extern "C" void kernel_launch(void* const* d_in, const int* in_sizes, int n_in,
                              void* d_out, int out_size, void* d_ws, size_t ws_size,
                              hipStream_t stream) {
    const float* node_feats = (const float*)d_in[0];
    const int*   edge_src   = (const int*)  d_in[1];
    const int*   edge_dst   = (const int*)  d_in[2];
    const float* edge_w     = (const float*)d_in[3];
    const float* W0         = (const float*)d_in[4];
    const float* b0         = (const float*)d_in[5];
    const float* W1         = (const float*)d_in[6];
    const float* b1         = (const float*)d_in[7];

    const int n_nodes = in_sizes[0] / D;   // 50000
    const int n_edges = in_sizes[1];       // 800000

    // workspace layout (all >=256B aligned)
    char* ws = (char*)d_ws;
    int*            row_off = (int*)ws;                        // 200004 B
    unsigned short* Wpack   = (unsigned short*)(ws + 204800);  // 16 KB
    const size_t base = 237568;
    unsigned short* X0 = (unsigned short*)(ws + base);             // 6.4 MB
    unsigned short* X1 = (unsigned short*)(ws + base + 6400000);   // 6.4 MB

    const int cvtb = (n_nodes * 16 + 255) / 256;          // 3125
    const int offb = (n_edges + 1 + 255) / 256;           // 3130
    prep_kernel<<<cvtb + 32 + offb, 256, 0, stream>>>(node_feats, edge_dst, W0, W1,
                                                      row_off, Wpack, X0,
                                                      n_nodes, n_edges, cvtb);

    const int ntiles = (n_nodes + 15) / 16;               // 3125

    layer_fused<0><<<ntiles, 256, 0, stream>>>(X0, row_off, edge_src, edge_w,
                                               Wpack, b0, b1, X1, n_nodes);
    layer_fused<1><<<ntiles, 256, 0, stream>>>(X1, row_off, edge_src, edge_w,
                                               Wpack, b0, b1, d_out, n_nodes);
}